// Round 15
// baseline (95.247 us; speedup 1.0000x reference)
//
#include <hip/hip_runtime.h>
#include <hip/hip_bf16.h>
#include <cstdint>

#define N_PTS 8192
#define DIM 128
// 32-row x 64-col wave tiles over the upper triangle (verified r7-r13).
// Row-tiles I in [0,256), col-tiles J in [0,128), jmin(I) = I>>1.
#define NBLK 16512

// Base-2-domain circle-loss constants (gamma=256, m=0.25, folded log2(e)).
#define KC2 369.3299304675746f    //  256*log2e
#define KC1 -738.6598609351493f   // -512*log2e
#define KC0 346.2468098133512f    //  240*log2e
#define KCN0 -23.083120654223414f // -16*log2e
#define NEGH -1e30f
#define LN2F 0.6931471805599453f

typedef __attribute__((ext_vector_type(8))) __bf16 bf16x8;
typedef __attribute__((ext_vector_type(4))) float f32x4;

// RNE float -> bf16 bits (inputs are finite, no NaN handling needed)
__device__ __forceinline__ unsigned short f2bf(float x) {
  unsigned int u = __float_as_uint(x);
  unsigned int r = (u + 0x7FFFu + ((u >> 16) & 1u)) >> 16;
  return (unsigned short)r;
}

// DPP wave reduction (rocPRIM idiom): row_shr 1/2/4/8 within 16-lane rows,
// then row_bcast15 / row_bcast31 across rows; lane 63 ends with the full
// 64-lane reduction. VALU-latency ops replace the 6-step ds_bpermute chains
// (~240cy serial DS latency -> ~60cy); readlane(63) gives a free SGPR
// broadcast for pass 2. CTRL must be a compile-time constant (r14 lesson:
// the builtin rejects runtime args) -> template parameter.
// max: old = v (invalid lanes reduce with themselves). add: old = 0.
template <int CTRL>
__device__ __forceinline__ float dpp_max(float v) {
  const int r = __builtin_amdgcn_update_dpp(__float_as_int(v), __float_as_int(v),
                                            CTRL, 0xF, 0xF, false);
  return fmaxf(v, __int_as_float(r));
}
template <int CTRL>
__device__ __forceinline__ float dpp_add(float v) {
  const int r = __builtin_amdgcn_update_dpp(0, __float_as_int(v), CTRL, 0xF, 0xF, false);
  return v + __int_as_float(r);
}
__device__ __forceinline__ float dpp_reduce_max(float v) {
  v = dpp_max<0x111>(v);  // row_shr:1
  v = dpp_max<0x112>(v);  // row_shr:2
  v = dpp_max<0x114>(v);  // row_shr:4
  v = dpp_max<0x118>(v);  // row_shr:8
  v = dpp_max<0x142>(v);  // row_bcast15
  v = dpp_max<0x143>(v);  // row_bcast31
  return v;
}
__device__ __forceinline__ float dpp_reduce_add(float v) {
  v = dpp_add<0x111>(v);
  v = dpp_add<0x112>(v);
  v = dpp_add<0x114>(v);
  v = dpp_add<0x118>(v);
  v = dpp_add<0x142>(v);
  v = dpp_add<0x143>(v);
  return v;
}
__device__ __forceinline__ float lane63(float v) {
  return __int_as_float(__builtin_amdgcn_readlane(__float_as_int(v), 63));
}

// PANEL-SWIZZLED feature layout (verified r11: the TA-coalescing fix).
// Panels of 16 rows; within panel (elems): [kk:4][kgrp:4][rsel:16][8].
//   addr(row, e) = (row>>4)*2048 + (e>>5)*512 + ((e>>3)&3)*128 + (row&15)*8 + (e&7)
// A fragment load becomes panel*2048 + kk*512 + lane*8: 64 lanes x 16B
// contiguous 1KiB, 16 lines/instr (was 64 lines/instr row-major -> the
// invariant ~40us TA wall of r6-r10).
__global__ __launch_bounds__(256) void normalize_kernel(const float* __restrict__ feat,
                                                        const int* __restrict__ labels,
                                                        unsigned short* __restrict__ fb2,
                                                        unsigned char* __restrict__ lab8) {
  const int gid = blockIdx.x * 256 + threadIdx.x;
  if (gid < N_PTS) lab8[gid] = (unsigned char)labels[gid];
  const int row = blockIdx.x * 8 + (threadIdx.x >> 5);
  const int l32 = threadIdx.x & 31;
  const float4 v = *(const float4*)(feat + row * DIM + l32 * 4);
  float ss = v.x * v.x + v.y * v.y + v.z * v.z + v.w * v.w;
#pragma unroll
  for (int o = 16; o > 0; o >>= 1) ss += __shfl_xor(ss, o);  // stays in 32-group
  const float inv = 1.0f / fmaxf(sqrtf(ss), 1e-12f);
  uint2 pack;
  pack.x = (unsigned int)f2bf(v.x * inv) | ((unsigned int)f2bf(v.y * inv) << 16);
  pack.y = (unsigned int)f2bf(v.z * inv) | ((unsigned int)f2bf(v.w * inv) << 16);
  const int e0 = l32 * 4;  // elems e0..e0+3 (one 8B half of a 16B chunk)
  const int dst = (row >> 4) * 2048 + (e0 >> 5) * 512 + ((e0 >> 3) & 3) * 128 +
                  (row & 15) * 8 + (e0 & 7);
  *(uint2*)(fb2 + dst) = pack;  // 8B aligned
}

// ---- tile machinery (verified r7-r13) ----
#define OFFI(I) (128 * (I) - (((I) - 1) * ((I) - 1)) / 4)
#define DECODE(TID, IV, JV)                                              \
  do {                                                                   \
    int _i = (int)(2.0f * (128.5f - sqrtf(16512.0f - (float)(TID))));    \
    _i = _i < 0 ? 0 : (_i > 255 ? 255 : _i);                             \
    while (OFFI(_i) > (TID)) --_i;                                       \
    while (OFFI(_i + 1) <= (TID)) ++_i;                                  \
    IV = _i;                                                             \
    JV = (_i >> 1) + ((TID)-OFFI(_i));                                   \
  } while (0)

// Wave-independent 32x64 tiles, zero LDS, zero barriers, panel-swizzled
// coalesced loads (r11) + 2-deep frag dbuf (r13). This round: DPP-based
// reductions replace the 4 serial 6-step ds_bpermute chains (the last
// unhidden latency component), and s_setprio(1) wraps the MFMA cluster
// (T5; independent-wave regime).
__global__ __launch_bounds__(256) void pair_kernel(const unsigned short* __restrict__ f,
                                                   const unsigned char* __restrict__ lab8,
                                                   float4* __restrict__ partials) {
  const int lane = threadIdx.x & 63;
  const int tid = blockIdx.x * 4 + (threadIdx.x >> 6);  // tile id, 0..NBLK-1

  int I, J;
  DECODE(tid, I, J);

  const int rsel = lane & 15, kgrp = lane >> 4;

  // panel-swizzled fragment pointers: contiguous 1KiB per fragment load
  const unsigned short* pA = f + (size_t)(I * 2) * 2048 + lane * 8;
  const unsigned short* pB = f + (size_t)(J * 4) * 2048 + lane * 8;

  // epilogue label gathers issued early; latency hides under the K-loop
  const int ibase = I * 32 + kgrp * 4;
  const int jbase = J * 64 + rsel;
  unsigned int liPack[2], ljPack = 0;
#pragma unroll
  for (int tn = 0; tn < 4; ++tn)
    ljPack |= ((unsigned int)lab8[jbase + tn * 16]) << (tn * 8);
#pragma unroll
  for (int tm = 0; tm < 2; ++tm)
    liPack[tm] = *(const unsigned int*)(lab8 + ibase + tm * 16);

  f32x4 acc[2][4];
#pragma unroll
  for (int a = 0; a < 2; ++a)
#pragma unroll
    for (int b = 0; b < 4; ++b) acc[a][b] = (f32x4){0.f, 0.f, 0.f, 0.f};

#define LOADF(FA, FB, KK)                                                \
  do {                                                                   \
    _Pragma("unroll") for (int x = 0; x < 2; ++x)                        \
        FA[x] = *(const bf16x8*)(pA + x * 2048 + (KK)*512);              \
    _Pragma("unroll") for (int x = 0; x < 4; ++x)                        \
        FB[x] = *(const bf16x8*)(pB + x * 2048 + (KK)*512);              \
  } while (0)
#define MFMA8(FA, FB)                                                    \
  do {                                                                   \
    _Pragma("unroll") for (int tm = 0; tm < 2; ++tm)                     \
        _Pragma("unroll") for (int tn = 0; tn < 4; ++tn)                 \
            acc[tm][tn] = __builtin_amdgcn_mfma_f32_16x16x32_bf16(       \
                FA[tm], FB[tn], acc[tm][tn], 0, 0, 0);                   \
  } while (0)

  {
    bf16x8 xa[2], xb[4], ya[2], yb[4];
    LOADF(xa, xb, 0);
    LOADF(ya, yb, 1);   // 2 K-steps in flight
    __builtin_amdgcn_s_setprio(1);
    MFMA8(xa, xb);
    __builtin_amdgcn_s_setprio(0);
    LOADF(xa, xb, 2);   // issued behind step-0 MFMAs, consumed 2 steps later
    __builtin_amdgcn_s_setprio(1);
    MFMA8(ya, yb);
    __builtin_amdgcn_s_setprio(0);
    LOADF(ya, yb, 3);
    __builtin_amdgcn_s_setprio(1);
    MFMA8(xa, xb);
    MFMA8(ya, yb);
    __builtin_amdgcn_s_setprio(0);
  }
#undef LOADF
#undef MFMA8

  // ---- epilogue: circle-loss logits (base-2 domain) + DPP logsumexp ----
  // C/D mapping (16x16x32): col = lane&15 (j/B side), row = (lane>>4)*4 + reg

  // pass 1: selected logit in-place, per-thread maxes
  float mp = NEGH, mn = NEGH;
  if (2 * J > I) {  // tile fully above the diagonal: all pairs valid (j > i)
#pragma unroll
    for (int tm = 0; tm < 2; ++tm)
#pragma unroll
      for (int tn = 0; tn < 4; ++tn) {
        const unsigned int ljB = (ljPack >> (tn * 8)) & 0xFFu;
#pragma unroll
        for (int r = 0; r < 4; ++r) {
          const float s = acc[tm][tn][r];
          const bool eq = (((liPack[tm] >> (r * 8)) & 0xFFu) == ljB);
          float u = fmaf(s, fmaf(s, KC2, eq ? KC1 : 0.f), eq ? KC0 : KCN0);
          u = (!eq && s <= -0.25f) ? 0.f : u;
          acc[tm][tn][r] = u;
          mp = fmaxf(mp, eq ? u : NEGH);
          mn = fmaxf(mn, eq ? NEGH : u);
        }
      }
  } else {  // diagonal-straddling tile: mask out j <= i
#pragma unroll
    for (int tm = 0; tm < 2; ++tm)
#pragma unroll
      for (int tn = 0; tn < 4; ++tn) {
        const unsigned int ljB = (ljPack >> (tn * 8)) & 0xFFu;
        const int d = (jbase + tn * 16) - (ibase + tm * 16);  // valid iff d > r
#pragma unroll
        for (int r = 0; r < 4; ++r) {
          const float s = acc[tm][tn][r];
          const bool eq = (((liPack[tm] >> (r * 8)) & 0xFFu) == ljB);
          float u = fmaf(s, fmaf(s, KC2, eq ? KC1 : 0.f), eq ? KC0 : KCN0);
          u = (!eq && s <= -0.25f) ? 0.f : u;
          const bool valid = d > r;
          u = valid ? u : NEGH;
          acc[tm][tn][r] = u;
          mp = fmaxf(mp, (eq && valid) ? u : NEGH);
          mn = fmaxf(mn, (!eq && valid) ? u : NEGH);
        }
      }
  }
  // DPP reduce; lane 63 -> SGPR broadcast. Clamp keeps exp2(NEGH-M)==0
  // when a stream is empty in this tile.
  mp = dpp_reduce_max(mp);
  mn = dpp_reduce_max(mn);
  const float Mp = fmaxf(lane63(mp), -1e28f);
  const float Mn = fmaxf(lane63(mn), -1e28f);

  // pass 2: one exp2 per element, route to the owning stream
  float sp = 0.f, sn = 0.f;
#pragma unroll
  for (int tm = 0; tm < 2; ++tm)
#pragma unroll
    for (int tn = 0; tn < 4; ++tn) {
      const unsigned int ljB = (ljPack >> (tn * 8)) & 0xFFu;
#pragma unroll
      for (int r = 0; r < 4; ++r) {
        const bool eq = (((liPack[tm] >> (r * 8)) & 0xFFu) == ljB);
        const float e = __builtin_amdgcn_exp2f(acc[tm][tn][r] - (eq ? Mp : Mn));
        sp += eq ? e : 0.f;
        sn += eq ? 0.f : e;
      }
    }
  sp = dpp_reduce_add(sp);
  sn = dpp_reduce_add(sn);
  const float sps = lane63(sp), sns = lane63(sn);
  if (lane == 0) partials[tid] = make_float4(Mp, sps, Mn, sns);
}

// Merge 16512 (m2,s2) base-2 partials for both streams; softplus(lse_p+lse_n).
__global__ __launch_bounds__(1024) void finalize_kernel(const float4* __restrict__ partials,
                                                        float* __restrict__ out) {
  const int t = threadIdx.x;
  float mp = NEGH, sp = 0.f, mn = NEGH, sn = 0.f;
  for (int i = t; i < NBLK; i += 1024) {
    const float4 p = partials[i];
    {
      const float m = fmaxf(mp, p.x);
      sp = sp * __builtin_amdgcn_exp2f(mp - m) + p.y * __builtin_amdgcn_exp2f(p.x - m);
      mp = m;
    }
    {
      const float m = fmaxf(mn, p.z);
      sn = sn * __builtin_amdgcn_exp2f(mn - m) + p.w * __builtin_amdgcn_exp2f(p.z - m);
      mn = m;
    }
  }
  __shared__ float smp[1024], ssp[1024], smn[1024], ssn[1024];
  smp[t] = mp; ssp[t] = sp; smn[t] = mn; ssn[t] = sn;
  __syncthreads();
  for (int off = 512; off > 0; off >>= 1) {
    if (t < off) {
      {
        const float m2 = smp[t + off], s2 = ssp[t + off];
        const float m = fmaxf(smp[t], m2);
        ssp[t] = ssp[t] * __builtin_amdgcn_exp2f(smp[t] - m) + s2 * __builtin_amdgcn_exp2f(m2 - m);
        smp[t] = m;
      }
      {
        const float m2 = smn[t + off], s2 = ssn[t + off];
        const float m = fmaxf(smn[t], m2);
        ssn[t] = ssn[t] * __builtin_amdgcn_exp2f(smn[t] - m) + s2 * __builtin_amdgcn_exp2f(m2 - m);
        smn[t] = m;
      }
    }
    __syncthreads();
  }
  if (t == 0) {
    const float lsep = (smp[0] + __builtin_amdgcn_logf(ssp[0])) * LN2F;  // base-2 -> nat
    const float lsen = (smn[0] + __builtin_amdgcn_logf(ssn[0])) * LN2F;
    const float x = lsep + lsen;
    out[0] = fmaxf(x, 0.f) + log1pf(__expf(-fabsf(x)));  // stable softplus
  }
}

extern "C" void kernel_launch(void* const* d_in, const int* in_sizes, int n_in,
                              void* d_out, int out_size, void* d_ws, size_t ws_size,
                              hipStream_t stream) {
  const float* feat = (const float*)d_in[0];
  const int* labels = (const int*)d_in[1];
  float* out = (float*)d_out;

  unsigned short* fb2 = (unsigned short*)d_ws;                       // 2 MiB (panel-swizzled)
  char* base = (char*)d_ws + (size_t)N_PTS * DIM * 2;
  float4* partials = (float4*)base;                                  // 16512*16 = 258 KiB
  unsigned char* lab8 = (unsigned char*)(base + (size_t)NBLK * 16);  // 8192 B

  normalize_kernel<<<N_PTS / 8, 256, 0, stream>>>(feat, labels, fb2, lab8);
  pair_kernel<<<NBLK / 4, 256, 0, stream>>>(fb2, lab8, partials);
  finalize_kernel<<<1, 1024, 0, stream>>>(partials, out);
}

// Round 16
// 90.377 us; speedup vs baseline: 1.0539x; 1.0539x over previous
//
#include <hip/hip_runtime.h>
#include <hip/hip_bf16.h>
#include <cstdint>

#define N_PTS 8192
#define DIM 128
// 32-row x 64-col wave tiles over the upper triangle (verified r7-r15).
// Row-tiles I in [0,256), col-tiles J in [0,128), jmin(I) = I>>1.
#define NBLK 16512
#define NPART (NBLK / 4)  // one merged partial per 4-wave block

// Base-2-domain circle-loss constants (gamma=256, m=0.25, folded log2(e)).
#define KC2 369.3299304675746f    //  256*log2e
#define KC1 -738.6598609351493f   // -512*log2e
#define KC0 346.2468098133512f    //  240*log2e
#define KCN0 -23.083120654223414f // -16*log2e
#define NEGH -1e30f
#define LN2F 0.6931471805599453f

typedef __attribute__((ext_vector_type(8))) __bf16 bf16x8;
typedef __attribute__((ext_vector_type(4))) float f32x4;

// RNE float -> bf16 bits (inputs are finite, no NaN handling needed)
__device__ __forceinline__ unsigned short f2bf(float x) {
  unsigned int u = __float_as_uint(x);
  unsigned int r = (u + 0x7FFFu + ((u >> 16) & 1u)) >> 16;
  return (unsigned short)r;
}

// DPP wave reduction (rocPRIM idiom; verified r15): row_shr 1/2/4/8 within
// 16-lane rows, then row_bcast15/31; lane 63 holds the 64-lane result.
// CTRL must be compile-time constant (r14 lesson) -> template parameter.
template <int CTRL>
__device__ __forceinline__ float dpp_max(float v) {
  const int r = __builtin_amdgcn_update_dpp(__float_as_int(v), __float_as_int(v),
                                            CTRL, 0xF, 0xF, false);
  return fmaxf(v, __int_as_float(r));
}
template <int CTRL>
__device__ __forceinline__ float dpp_add(float v) {
  const int r = __builtin_amdgcn_update_dpp(0, __float_as_int(v), CTRL, 0xF, 0xF, false);
  return v + __int_as_float(r);
}
__device__ __forceinline__ float dpp_reduce_max(float v) {
  v = dpp_max<0x111>(v);
  v = dpp_max<0x112>(v);
  v = dpp_max<0x114>(v);
  v = dpp_max<0x118>(v);
  v = dpp_max<0x142>(v);
  v = dpp_max<0x143>(v);
  return v;
}
__device__ __forceinline__ float dpp_reduce_add(float v) {
  v = dpp_add<0x111>(v);
  v = dpp_add<0x112>(v);
  v = dpp_add<0x114>(v);
  v = dpp_add<0x118>(v);
  v = dpp_add<0x142>(v);
  v = dpp_add<0x143>(v);
  return v;
}
__device__ __forceinline__ float lane63(float v) {
  return __int_as_float(__builtin_amdgcn_readlane(__float_as_int(v), 63));
}

// PANEL-SWIZZLED feature layout (verified r11: the TA-coalescing fix).
// Panels of 16 rows; within panel (elems): [kk:4][kgrp:4][rsel:16][8].
//   addr(row, e) = (row>>4)*2048 + (e>>5)*512 + ((e>>3)&3)*128 + (row&15)*8 + (e&7)
// A fragment load becomes panel*2048 + kk*512 + lane*8: 64 lanes x 16B
// contiguous 1KiB, 16 lines/instr (was 64 lines/instr row-major -> the
// invariant ~40us TA wall of r6-r10).
__global__ __launch_bounds__(256) void normalize_kernel(const float* __restrict__ feat,
                                                        const int* __restrict__ labels,
                                                        unsigned short* __restrict__ fb2,
                                                        unsigned char* __restrict__ lab8) {
  const int gid = blockIdx.x * 256 + threadIdx.x;
  if (gid < N_PTS) lab8[gid] = (unsigned char)labels[gid];
  const int row = blockIdx.x * 8 + (threadIdx.x >> 5);
  const int l32 = threadIdx.x & 31;
  const float4 v = *(const float4*)(feat + row * DIM + l32 * 4);
  float ss = v.x * v.x + v.y * v.y + v.z * v.z + v.w * v.w;
#pragma unroll
  for (int o = 16; o > 0; o >>= 1) ss += __shfl_xor(ss, o);  // stays in 32-group
  const float inv = 1.0f / fmaxf(sqrtf(ss), 1e-12f);
  uint2 pack;
  pack.x = (unsigned int)f2bf(v.x * inv) | ((unsigned int)f2bf(v.y * inv) << 16);
  pack.y = (unsigned int)f2bf(v.z * inv) | ((unsigned int)f2bf(v.w * inv) << 16);
  const int e0 = l32 * 4;  // elems e0..e0+3 (one 8B half of a 16B chunk)
  const int dst = (row >> 4) * 2048 + (e0 >> 5) * 512 + ((e0 >> 3) & 3) * 128 +
                  (row & 15) * 8 + (e0 & 7);
  *(uint2*)(fb2 + dst) = pack;  // 8B aligned
}

// ---- tile machinery (verified r7-r15) ----
#define OFFI(I) (128 * (I) - (((I) - 1) * ((I) - 1)) / 4)
#define DECODE(TID, IV, JV)                                              \
  do {                                                                   \
    int _i = (int)(2.0f * (128.5f - sqrtf(16512.0f - (float)(TID))));    \
    _i = _i < 0 ? 0 : (_i > 255 ? 255 : _i);                             \
    while (OFFI(_i) > (TID)) --_i;                                       \
    while (OFFI(_i + 1) <= (TID)) ++_i;                                  \
    IV = _i;                                                             \
    JV = (_i >> 1) + ((TID)-OFFI(_i));                                   \
  } while (0)

// Wave-independent 32x64 tiles, panel-swizzled coalesced loads (r11) +
// 2-deep frag dbuf (r13) + DPP reductions (r15). This round: the 4 waves of
// each block merge their partials through 64B of LDS (2 trailing barriers)
// so pair emits ONE partial per block -> finalize reads 4x less and runs
// 4x fewer serial merge rounds.
__global__ __launch_bounds__(256) void pair_kernel(const unsigned short* __restrict__ f,
                                                   const unsigned char* __restrict__ lab8,
                                                   float4* __restrict__ partials) {
  __shared__ float red[4][4];  // [wave][Mp, sp, Mn, sn]
  const int lane = threadIdx.x & 63;
  const int wave = threadIdx.x >> 6;
  const int tid = blockIdx.x * 4 + wave;  // tile id, 0..NBLK-1

  int I, J;
  DECODE(tid, I, J);

  const int rsel = lane & 15, kgrp = lane >> 4;

  // panel-swizzled fragment pointers: contiguous 1KiB per fragment load
  const unsigned short* pA = f + (size_t)(I * 2) * 2048 + lane * 8;
  const unsigned short* pB = f + (size_t)(J * 4) * 2048 + lane * 8;

  // epilogue label gathers issued early; latency hides under the K-loop
  const int ibase = I * 32 + kgrp * 4;
  const int jbase = J * 64 + rsel;
  unsigned int liPack[2], ljPack = 0;
#pragma unroll
  for (int tn = 0; tn < 4; ++tn)
    ljPack |= ((unsigned int)lab8[jbase + tn * 16]) << (tn * 8);
#pragma unroll
  for (int tm = 0; tm < 2; ++tm)
    liPack[tm] = *(const unsigned int*)(lab8 + ibase + tm * 16);

  f32x4 acc[2][4];
#pragma unroll
  for (int a = 0; a < 2; ++a)
#pragma unroll
    for (int b = 0; b < 4; ++b) acc[a][b] = (f32x4){0.f, 0.f, 0.f, 0.f};

#define LOADF(FA, FB, KK)                                                \
  do {                                                                   \
    _Pragma("unroll") for (int x = 0; x < 2; ++x)                        \
        FA[x] = *(const bf16x8*)(pA + x * 2048 + (KK)*512);              \
    _Pragma("unroll") for (int x = 0; x < 4; ++x)                        \
        FB[x] = *(const bf16x8*)(pB + x * 2048 + (KK)*512);              \
  } while (0)
#define MFMA8(FA, FB)                                                    \
  do {                                                                   \
    _Pragma("unroll") for (int tm = 0; tm < 2; ++tm)                     \
        _Pragma("unroll") for (int tn = 0; tn < 4; ++tn)                 \
            acc[tm][tn] = __builtin_amdgcn_mfma_f32_16x16x32_bf16(       \
                FA[tm], FB[tn], acc[tm][tn], 0, 0, 0);                   \
  } while (0)

  {
    bf16x8 xa[2], xb[4], ya[2], yb[4];
    LOADF(xa, xb, 0);
    LOADF(ya, yb, 1);   // 2 K-steps in flight
    __builtin_amdgcn_s_setprio(1);
    MFMA8(xa, xb);
    __builtin_amdgcn_s_setprio(0);
    LOADF(xa, xb, 2);   // issued behind step-0 MFMAs, consumed 2 steps later
    __builtin_amdgcn_s_setprio(1);
    MFMA8(ya, yb);
    __builtin_amdgcn_s_setprio(0);
    LOADF(ya, yb, 3);
    __builtin_amdgcn_s_setprio(1);
    MFMA8(xa, xb);
    MFMA8(ya, yb);
    __builtin_amdgcn_s_setprio(0);
  }
#undef LOADF
#undef MFMA8

  // ---- epilogue: circle-loss logits (base-2 domain) + DPP logsumexp ----
  // C/D mapping (16x16x32): col = lane&15 (j/B side), row = (lane>>4)*4 + reg

  // pass 1: selected logit in-place, per-thread maxes
  float mp = NEGH, mn = NEGH;
  if (2 * J > I) {  // tile fully above the diagonal: all pairs valid (j > i)
#pragma unroll
    for (int tm = 0; tm < 2; ++tm)
#pragma unroll
      for (int tn = 0; tn < 4; ++tn) {
        const unsigned int ljB = (ljPack >> (tn * 8)) & 0xFFu;
#pragma unroll
        for (int r = 0; r < 4; ++r) {
          const float s = acc[tm][tn][r];
          const bool eq = (((liPack[tm] >> (r * 8)) & 0xFFu) == ljB);
          float u = fmaf(s, fmaf(s, KC2, eq ? KC1 : 0.f), eq ? KC0 : KCN0);
          u = (!eq && s <= -0.25f) ? 0.f : u;
          acc[tm][tn][r] = u;
          mp = fmaxf(mp, eq ? u : NEGH);
          mn = fmaxf(mn, eq ? NEGH : u);
        }
      }
  } else {  // diagonal-straddling tile: mask out j <= i
#pragma unroll
    for (int tm = 0; tm < 2; ++tm)
#pragma unroll
      for (int tn = 0; tn < 4; ++tn) {
        const unsigned int ljB = (ljPack >> (tn * 8)) & 0xFFu;
        const int d = (jbase + tn * 16) - (ibase + tm * 16);  // valid iff d > r
#pragma unroll
        for (int r = 0; r < 4; ++r) {
          const float s = acc[tm][tn][r];
          const bool eq = (((liPack[tm] >> (r * 8)) & 0xFFu) == ljB);
          float u = fmaf(s, fmaf(s, KC2, eq ? KC1 : 0.f), eq ? KC0 : KCN0);
          u = (!eq && s <= -0.25f) ? 0.f : u;
          const bool valid = d > r;
          u = valid ? u : NEGH;
          acc[tm][tn][r] = u;
          mp = fmaxf(mp, (eq && valid) ? u : NEGH);
          mn = fmaxf(mn, (!eq && valid) ? u : NEGH);
        }
      }
  }
  // DPP reduce; lane 63 -> SGPR broadcast. Clamp keeps exp2(NEGH-M)==0
  // when a stream is empty in this tile.
  mp = dpp_reduce_max(mp);
  mn = dpp_reduce_max(mn);
  const float Mp = fmaxf(lane63(mp), -1e28f);
  const float Mn = fmaxf(lane63(mn), -1e28f);

  // pass 2: one exp2 per element, route to the owning stream
  float sp = 0.f, sn = 0.f;
#pragma unroll
  for (int tm = 0; tm < 2; ++tm)
#pragma unroll
    for (int tn = 0; tn < 4; ++tn) {
      const unsigned int ljB = (ljPack >> (tn * 8)) & 0xFFu;
#pragma unroll
      for (int r = 0; r < 4; ++r) {
        const bool eq = (((liPack[tm] >> (r * 8)) & 0xFFu) == ljB);
        const float e = __builtin_amdgcn_exp2f(acc[tm][tn][r] - (eq ? Mp : Mn));
        sp += eq ? e : 0.f;
        sn += eq ? 0.f : e;
      }
    }
  sp = dpp_reduce_add(sp);
  sn = dpp_reduce_add(sn);

  // ---- block-level merge: 4 wave partials -> 1 per block ----
  if (lane == 63) {  // lane 63 holds the DPP results
    red[wave][0] = Mp; red[wave][1] = sp; red[wave][2] = Mn; red[wave][3] = sn;
  }
  __syncthreads();
  if (threadIdx.x == 0) {
    float bMp = NEGH, bsp = 0.f, bMn = NEGH, bsn = 0.f;
#pragma unroll
    for (int w = 0; w < 4; ++w) {
      {
        const float m2 = red[w][0], s2 = red[w][1];
        const float m = fmaxf(bMp, m2);
        bsp = bsp * __builtin_amdgcn_exp2f(bMp - m) + s2 * __builtin_amdgcn_exp2f(m2 - m);
        bMp = m;
      }
      {
        const float m2 = red[w][2], s2 = red[w][3];
        const float m = fmaxf(bMn, m2);
        bsn = bsn * __builtin_amdgcn_exp2f(bMn - m) + s2 * __builtin_amdgcn_exp2f(m2 - m);
        bMn = m;
      }
    }
    partials[blockIdx.x] = make_float4(bMp, bsp, bMn, bsn);
  }
}

// Merge 4128 (m2,s2) base-2 partials for both streams; softplus(lse_p+lse_n).
__global__ __launch_bounds__(1024) void finalize_kernel(const float4* __restrict__ partials,
                                                        float* __restrict__ out) {
  const int t = threadIdx.x;
  float mp = NEGH, sp = 0.f, mn = NEGH, sn = 0.f;
  for (int i = t; i < NPART; i += 1024) {
    const float4 p = partials[i];
    {
      const float m = fmaxf(mp, p.x);
      sp = sp * __builtin_amdgcn_exp2f(mp - m) + p.y * __builtin_amdgcn_exp2f(p.x - m);
      mp = m;
    }
    {
      const float m = fmaxf(mn, p.z);
      sn = sn * __builtin_amdgcn_exp2f(mn - m) + p.w * __builtin_amdgcn_exp2f(p.z - m);
      mn = m;
    }
  }
  __shared__ float smp[1024], ssp[1024], smn[1024], ssn[1024];
  smp[t] = mp; ssp[t] = sp; smn[t] = mn; ssn[t] = sn;
  __syncthreads();
  for (int off = 512; off > 0; off >>= 1) {
    if (t < off) {
      {
        const float m2 = smp[t + off], s2 = ssp[t + off];
        const float m = fmaxf(smp[t], m2);
        ssp[t] = ssp[t] * __builtin_amdgcn_exp2f(smp[t] - m) + s2 * __builtin_amdgcn_exp2f(m2 - m);
        smp[t] = m;
      }
      {
        const float m2 = smn[t + off], s2 = ssn[t + off];
        const float m = fmaxf(smn[t], m2);
        ssn[t] = ssn[t] * __builtin_amdgcn_exp2f(smn[t] - m) + s2 * __builtin_amdgcn_exp2f(m2 - m);
        smn[t] = m;
      }
    }
    __syncthreads();
  }
  if (t == 0) {
    const float lsep = (smp[0] + __builtin_amdgcn_logf(ssp[0])) * LN2F;  // base-2 -> nat
    const float lsen = (smn[0] + __builtin_amdgcn_logf(ssn[0])) * LN2F;
    const float x = lsep + lsen;
    out[0] = fmaxf(x, 0.f) + log1pf(__expf(-fabsf(x)));  // stable softplus
  }
}

extern "C" void kernel_launch(void* const* d_in, const int* in_sizes, int n_in,
                              void* d_out, int out_size, void* d_ws, size_t ws_size,
                              hipStream_t stream) {
  const float* feat = (const float*)d_in[0];
  const int* labels = (const int*)d_in[1];
  float* out = (float*)d_out;

  unsigned short* fb2 = (unsigned short*)d_ws;                        // 2 MiB (panel-swizzled)
  char* base = (char*)d_ws + (size_t)N_PTS * DIM * 2;
  float4* partials = (float4*)base;                                   // 4128*16 = 66 KiB
  unsigned char* lab8 = (unsigned char*)(base + (size_t)NPART * 16);  // 8192 B

  normalize_kernel<<<N_PTS / 8, 256, 0, stream>>>(feat, labels, fb2, lab8);
  pair_kernel<<<NBLK / 4, 256, 0, stream>>>(fb2, lab8, partials);
  finalize_kernel<<<1, 1024, 0, stream>>>(partials, out);
}